// Round 10
// baseline (68.544 us; speedup 1.0000x reference)
//
#include <hip/hip_runtime.h>
#include <hip/hip_bf16.h>
#include <stdint.h>

typedef unsigned short u16;
typedef __attribute__((ext_vector_type(8))) short bf16x8;
typedef __attribute__((ext_vector_type(4))) float f32x4;
typedef __attribute__((ext_vector_type(2))) float f32x2;
typedef __attribute__((ext_vector_type(4))) unsigned int u32x4;
typedef __attribute__((ext_vector_type(2))) unsigned int u32x2;

#define NTOK 4096
#define NT64 64   // 4096 / 64 t2-tiles

#if __has_builtin(__builtin_amdgcn_exp2f)
#define EXP2F __builtin_amdgcn_exp2f
#else
#define EXP2F exp2f
#endif

__device__ __forceinline__ f32x4 MFMA(bf16x8 a, bf16x8 b, f32x4 c) {
    return __builtin_amdgcn_mfma_f32_16x16x32_bf16(a, b, c, 0, 0, 0);
}

// packed f32->bf16 (D.lo = bf16(a), D.hi = bf16(b))
__device__ __forceinline__ uint32_t pk_bf16(float a, float b) {
    uint32_t d;
    asm("v_cvt_pk_bf16_f32 %0, %1, %2" : "=v"(d) : "v"(a), "v"(b));
    return d;
}

// truncation hi/lo split of 8 floats into two bf16x8 fragments
__device__ __forceinline__ void hilo_pack8(const float* v, bf16x8* h, bf16x8* l) {
    union { uint32_t u[4]; bf16x8 b; } H, L;
#pragma unroll
    for (int m = 0; m < 4; ++m) {
        const uint32_t ua = __float_as_uint(v[2*m]);
        const uint32_t ub = __float_as_uint(v[2*m+1]);
        const float la = v[2*m]   - __uint_as_float(ua & 0xffff0000u);
        const float lb = v[2*m+1] - __uint_as_float(ub & 0xffff0000u);
        H.u[m] = (ua >> 16) | (ub & 0xffff0000u);
        L.u[m] = (__float_as_uint(la) >> 16) | (__float_as_uint(lb) & 0xffff0000u);
    }
    *h = H.b; *l = L.b;
}

__device__ __forceinline__ void async_copy16(void* lds_dst, const void* g_src) {
    __builtin_amdgcn_global_load_lds(
        (const __attribute__((address_space(1))) uint32_t*)g_src,
        (__attribute__((address_space(3))) uint32_t*)lds_dst, 16, 0, 0);
}

// ---------------------------------------------------------------------------
// k_qkv: QKV projection via MFMA (w,x hi/lo 3-term), then repack through LDS.
// (unchanged)
// ---------------------------------------------------------------------------
__global__ __launch_bounds__(256) void k_qkv(
    const float* __restrict__ x, const float* __restrict__ wqkv, const float* __restrict__ bqkv,
    u16* __restrict__ Qp, u16* __restrict__ Kp, u16* __restrict__ Vp)
{
    __shared__ float qt_lds[64 * 194];
    const int blk = blockIdx.x;
    const int b   = blk >> 6;
    const int tb  = (blk & 63) << 6;
    const int tid = threadIdx.x;
    const int lane = tid & 63;
    const int wv  = __builtin_amdgcn_readfirstlane(tid >> 6);
    const int r   = lane & 15;
    const int g   = lane >> 4;
    const int o0  = wv * 48;

    bf16x8 wh[3][2], wl[3][2];
#pragma unroll
    for (int oi = 0; oi < 3; ++oi)
#pragma unroll
        for (int ks = 0; ks < 2; ++ks) {
            const float* wp = wqkv + (size_t)(o0 + oi*16 + r) * 64 + ks*32 + g*8;
            float wv8[8];
            *(f32x4*)(wv8)     = *(const f32x4*)(wp);
            *(f32x4*)(wv8 + 4) = *(const f32x4*)(wp + 4);
            hilo_pack8(wv8, &wh[oi][ks], &wl[oi][ks]);
        }

    f32x4 acc[3][4];
#pragma unroll
    for (int oi = 0; oi < 3; ++oi)
#pragma unroll
        for (int tt = 0; tt < 4; ++tt) acc[oi][tt] = 0.f;

#pragma unroll
    for (int tt = 0; tt < 4; ++tt) {
        bf16x8 xh[2], xl[2];
#pragma unroll
        for (int ks = 0; ks < 2; ++ks) {
            float xv[8];
#pragma unroll
            for (int j = 0; j < 8; ++j)
                xv[j] = x[(size_t)(b*64 + ks*32 + g*8 + j) * NTOK + tb + tt*16 + r];
            hilo_pack8(xv, &xh[ks], &xl[ks]);
        }
#pragma unroll
        for (int oi = 0; oi < 3; ++oi) {
            f32x4 a = acc[oi][tt];
            a = MFMA(wh[oi][0], xh[0], a);
            a = MFMA(wh[oi][1], xh[1], a);
            a = MFMA(wl[oi][0], xh[0], a);
            a = MFMA(wl[oi][1], xh[1], a);
            a = MFMA(wh[oi][0], xl[0], a);
            a = MFMA(wh[oi][1], xl[1], a);
            acc[oi][tt] = a;
        }
    }

#pragma unroll
    for (int oi = 0; oi < 3; ++oi)
#pragma unroll
        for (int tt = 0; tt < 4; ++tt)
#pragma unroll
            for (int i = 0; i < 4; ++i)
                qt_lds[(tt*16 + r) * 194 + o0 + oi*16 + g*4 + i] = acc[oi][tt][i];
    __syncthreads();

    const float SC = 0.18033688011112042f;  // (1/8) * log2(e)

    {
        const int t = tid >> 2, c0 = (tid & 3) * 16;
        float v[16], bq[16];
#pragma unroll
        for (int m = 0; m < 8; ++m)
            *(f32x2*)(v + 2*m) = *(const f32x2*)&qt_lds[t*194 + c0 + 2*m];
#pragma unroll
        for (int m = 0; m < 4; ++m)
            *(f32x4*)(bq + 4*m) = *(const f32x4*)(bqkv + c0 + 4*m);
        u32x4 P0, P1;
#pragma unroll
        for (int m = 0; m < 4; ++m) {
            P0[m] = pk_bf16((v[2*m]   + bq[2*m]  ) * SC, (v[2*m+1] + bq[2*m+1]) * SC);
            P1[m] = pk_bf16((v[8+2*m] + bq[8+2*m]) * SC, (v[9+2*m] + bq[9+2*m]) * SC);
        }
        size_t base = ((size_t)(b * NTOK + tb + t)) * 64 + c0;
        *(u32x4*)(Qp + base)     = P0;
        *(u32x4*)(Qp + base + 8) = P1;
    }

#pragma unroll
    for (int uu = 0; uu < 2; ++uu) {
        const int u  = tid * 2 + uu;
        const int t  = u >> 3;
        const int ks = (u >> 2) & 1;
        const int gk = u & 3;
        const int cb0 = 64 + ks*32 + gk*8;
        float v[8];
#pragma unroll
        for (int m = 0; m < 4; ++m)
            *(f32x2*)(v + 2*m) = *(const f32x2*)&qt_lds[t*194 + cb0 + 2*m];
        u32x4 P;
#pragma unroll
        for (int m = 0; m < 4; ++m)
            P[m] = pk_bf16(v[2*m] + bqkv[cb0 + 2*m], v[2*m+1] + bqkv[cb0 + 2*m+1]);
        const int tg = tb + t;
        size_t kbase = (size_t)b * 262144 + ((size_t)(tg >> 4) * 2 + ks) * 512 + gk*128 + (t & 15) * 8;
        *(u32x4*)(Kp + kbase) = P;
    }

    {
        const int cb = (tid >> 4) & 3;
        const int r2 = tid & 15;
        const float bv = bqkv[128 + cb*16 + r2];
        const int T = (blk & 63) >> 1;
        const int halfb = blk & 1;
#pragma unroll
        for (int m = 0; m < 4; ++m) {
            const int tq = m * 4 + (tid >> 6);
            float v[4];
#pragma unroll
            for (int jj = 0; jj < 4; ++jj)
                v[jj] = qt_lds[(tq*4 + jj)*194 + 128 + cb*16 + r2] + bv;
            const int t = tq * 4;
            const int wtr = halfb*2 + (t >> 5);
            const int sti = (t >> 4) & 1;
            const int g2  = (t >> 2) & 3;
            u32x2 W;
            W[0] = pk_bf16(v[0], v[1]);
            W[1] = pk_bf16(v[2], v[3]);
            size_t vbase = (size_t)b * 262144 +
                           (((size_t)T * 4 + wtr) * 4 + cb) * 512 + (g2*16 + r2) * 8 + sti * 4;
            *(u32x2*)(Vp + vbase) = W;
        }
    }
}

// ---------------------------------------------------------------------------
// k_attn: flash attention, fixed-shift softmax, LDS-staged K/V shared by
// 2 Q-groups (halves L2 traffic vs R9's 32 B/cyc/CU wall).
// grid 512 = 8 b x 64 row-blocks (64 Q-rows); block 256 = 4 waves
// = 2 Q-groups (32 rows) x 2 t2-slices (32 of the 64-t2 tile).
// Per iter: stage next 16 KB tile (global_load_lds w16, double-buffered),
// ds_read_b128 current tile, QK -> exp2 -> PV/l, vmcnt(0)+one barrier.
// 2-way split-l merge (plain sums) + fused out-projection + residual.
// ---------------------------------------------------------------------------
__global__ __launch_bounds__(256, 2) void k_attn(
    const u16* __restrict__ Qp, const u16* __restrict__ Kp, const u16* __restrict__ Vp,
    const float* __restrict__ wout, const float* __restrict__ bout,
    const float* __restrict__ x, float* __restrict__ out)
{
    __shared__ __align__(16) char kv[2][16384];   // [buf][K 8KB | V 8KB]
    __shared__ float otbuf[64 * 67];
    __shared__ float larr[2][64];
    const int hw  = blockIdx.x;
    const int b   = hw & 7;        // batch -> XCD pinning
    const int qb  = hw >> 3;       // 0..63 row-block
    const int row0 = qb * 64;
    const int tid = threadIdx.x;
    const int lane = tid & 63;
    const int wv  = tid >> 6;      // 0..3
    const int wq2 = wv >> 1;       // Q-group (32 rows)
    const int wt  = wv & 1;        // t2-slice (32 of 64)
    const int r   = lane & 15;
    const int g   = lane >> 4;

    // Q fragments (B operand), rows row0 + wq2*32 + rt*16 + r
    bf16x8 qh[2][2];
#pragma unroll
    for (int rt = 0; rt < 2; ++rt) {
        const size_t qoff = ((size_t)(b * NTOK + row0 + wq2*32 + rt*16 + r)) * 64 + g * 8;
        qh[rt][0] = *(const bf16x8*)(Qp + qoff);
        qh[rt][1] = *(const bf16x8*)(Qp + qoff + 32);
    }

    // 64-t2 tile t: K = Kp[b] + t*4096 elems (8KB), V = Vp[b] + t*4096 (8KB)
    const char* gK = (const char*)(Kp + (size_t)b * 262144);
    const char* gV = (const char*)(Vp + (size_t)b * 262144);

    auto stage = [&](int T, int buf) {
        char* dst = kv[buf] + tid * 16;
        const char* sK = gK + (size_t)T * 8192 + tid * 16;
        const char* sV = gV + (size_t)T * 8192 + tid * 16;
        async_copy16(dst,         sK);
        async_copy16(dst + 4096,  sK + 4096);
        async_copy16(dst + 8192,  sV);
        async_copy16(dst + 12288, sV + 4096);
    };

    // iter-invariant LDS byte offsets for this wave's slice
    int koff[2][2], voff[4];
#pragma unroll
    for (int sti = 0; sti < 2; ++sti)
#pragma unroll
        for (int ks = 0; ks < 2; ++ks)
            koff[sti][ks] = ((2*wt + sti)*2 + ks)*1024 + lane*16;
#pragma unroll
    for (int cb = 0; cb < 4; ++cb)
        voff[cb] = 8192 + (wt*4 + cb)*1024 + lane*16;

    // ones B-fragment for row-sum MFMA
    bf16x8 ONES;
#pragma unroll
    for (int j = 0; j < 8; ++j) ONES[j] = (short)0x3F80;

    f32x4 oacc[2][4];
#pragma unroll
    for (int rt = 0; rt < 2; ++rt)
#pragma unroll
        for (int cb = 0; cb < 4; ++cb) oacc[rt][cb] = 0.f;
    f32x4 lacc[2];
    lacc[0] = 0.f; lacc[1] = 0.f;

    stage(0, 0);
    asm volatile("s_waitcnt vmcnt(0)" ::: "memory");
    __syncthreads();
    int cur = 0;

    for (int T = 0; T < NT64; ++T) {
        if (T + 1 < NT64) stage(T + 1, cur ^ 1);

        const char* bufp = kv[cur];
        bf16x8 kc[2][2];
#pragma unroll
        for (int sti = 0; sti < 2; ++sti)
#pragma unroll
            for (int ks = 0; ks < 2; ++ks)
                kc[sti][ks] = *(const bf16x8*)(bufp + koff[sti][ks]);
        bf16x8 vf[4];
#pragma unroll
        for (int cb = 0; cb < 4; ++cb)
            vf[cb] = *(const bf16x8*)(bufp + voff[cb]);

        // QK^T
        f32x4 s[2][2];
        __builtin_amdgcn_s_setprio(1);
#pragma unroll
        for (int rt = 0; rt < 2; ++rt)
#pragma unroll
            for (int sti = 0; sti < 2; ++sti) {
                f32x4 a = {0.f, 0.f, 0.f, 0.f};
                a = MFMA(kc[sti][0], qh[rt][0], a);
                a = MFMA(kc[sti][1], qh[rt][1], a);
                s[rt][sti] = a;
            }
        __builtin_amdgcn_s_setprio(0);

        // fixed-shift softmax: p = exp2(S); PV + l accumulate
#pragma unroll
        for (int rt = 0; rt < 2; ++rt) {
            float p[8];
#pragma unroll
            for (int sti = 0; sti < 2; ++sti)
#pragma unroll
                for (int i = 0; i < 4; ++i)
                    p[sti*4 + i] = EXP2F(s[rt][sti][i]);
            union { uint32_t u[4]; bf16x8 b; } PA;
#pragma unroll
            for (int m = 0; m < 4; ++m) PA.u[m] = pk_bf16(p[2*m], p[2*m+1]);
            __builtin_amdgcn_s_setprio(1);
#pragma unroll
            for (int cb = 0; cb < 4; ++cb)
                oacc[rt][cb] = MFMA(PA.b, vf[cb], oacc[rt][cb]);
            lacc[rt] = MFMA(PA.b, ONES, lacc[rt]);
            __builtin_amdgcn_s_setprio(0);
        }

        asm volatile("s_waitcnt vmcnt(0)" ::: "memory");
        __syncthreads();
        cur ^= 1;
    }

    // ---- epilogue: 2-way slice merge (plain sums; shift-exact softmax) ----
    if (r == 0) {
#pragma unroll
        for (int rt = 0; rt < 2; ++rt)
#pragma unroll
            for (int i = 0; i < 4; ++i)
                larr[wt][wq2*32 + rt*16 + g*4 + i] = lacc[rt][i];
    }

    // accumulate raw O partials (64 rows x 64 cols): wt=0 write, wt=1 add
    if (wt == 0) {
#pragma unroll
        for (int rt = 0; rt < 2; ++rt)
#pragma unroll
            for (int cb = 0; cb < 4; ++cb)
#pragma unroll
                for (int i = 0; i < 4; ++i)
                    otbuf[(wq2*32 + rt*16 + g*4 + i)*67 + cb*16 + r] = oacc[rt][cb][i];
    }
    __syncthreads();
    if (wt == 1) {
#pragma unroll
        for (int rt = 0; rt < 2; ++rt)
#pragma unroll
            for (int cb = 0; cb < 4; ++cb)
#pragma unroll
                for (int i = 0; i < 4; ++i)
                    otbuf[(wq2*32 + rt*16 + g*4 + i)*67 + cb*16 + r] += oacc[rt][cb][i];
    }
    __syncthreads();

    // ---- fused out-projection + bias + residual ----
    // wave wv handles block-local token rows wv*16 + r, all 64 outputs
    const int orow = wv*16 + r;
    const float inv = 1.0f / (larr[0][orow] + larr[1][orow]);
    bf16x8 oh_[2], ol_[2];
#pragma unroll
    for (int ks = 0; ks < 2; ++ks) {
        float ov[8];
#pragma unroll
        for (int j = 0; j < 8; ++j)
            ov[j] = otbuf[orow*67 + ks*32 + g*8 + j] * inv;
        hilo_pack8(ov, &oh_[ks], &ol_[ks]);
    }
#pragma unroll
    for (int ot = 0; ot < 4; ++ot) {
        bf16x8 wh2[2], wl2[2];
#pragma unroll
        for (int ks = 0; ks < 2; ++ks) {
            const float* wp = wout + (size_t)(ot*16 + r) * 64 + ks*32 + g*8;
            float wv8[8];
            *(f32x4*)(wv8)     = *(const f32x4*)(wp);
            *(f32x4*)(wv8 + 4) = *(const f32x4*)(wp + 4);
            hilo_pack8(wv8, &wh2[ks], &wl2[ks]);
        }
        f32x4 a = {0.f, 0.f, 0.f, 0.f};
        a = MFMA(wh2[0], oh_[0], a);
        a = MFMA(wh2[1], oh_[1], a);
        a = MFMA(wl2[0], oh_[0], a);
        a = MFMA(wl2[1], oh_[1], a);
        a = MFMA(wh2[0], ol_[0], a);
        a = MFMA(wh2[1], ol_[1], a);
#pragma unroll
        for (int i = 0; i < 4; ++i) {
            const int oo = ot*16 + g*4 + i;
            const size_t xi = ((size_t)(b*64 + oo)) * NTOK + row0 + wv*16 + r;
            out[xi] = a[i] + bout[oo] + x[xi];
        }
    }
}

extern "C" void kernel_launch(void* const* d_in, const int* in_sizes, int n_in,
                              void* d_out, int out_size, void* d_ws, size_t ws_size,
                              hipStream_t stream)
{
    (void)in_sizes; (void)n_in; (void)out_size; (void)ws_size;
    const float* x    = (const float*)d_in[0];
    const float* wqkv = (const float*)d_in[1];
    const float* bqkv = (const float*)d_in[2];
    const float* wout = (const float*)d_in[3];
    const float* bout = (const float*)d_in[4];
    float* out = (float*)d_out;

    char* ws = (char*)d_ws;
    const size_t MB = 1024 * 1024;
    u16* Qp = (u16*)(ws);
    u16* Kp = (u16*)(ws + 4 * MB);
    u16* Vp = (u16*)(ws + 8 * MB);

    k_qkv<<<512, 256, 0, stream>>>(x, wqkv, bqkv, Qp, Kp, Vp);
    k_attn<<<512, 256, 0, stream>>>(Qp, Kp, Vp, wout, bout, x, out);
}

// Round 11
// 53.971 us; speedup vs baseline: 1.2700x; 1.2700x over previous
//
#include <hip/hip_runtime.h>
#include <hip/hip_bf16.h>
#include <stdint.h>

typedef unsigned short u16;
typedef __attribute__((ext_vector_type(8))) short bf16x8;
typedef __attribute__((ext_vector_type(4))) float f32x4;
typedef __attribute__((ext_vector_type(2))) float f32x2;
typedef __attribute__((ext_vector_type(4))) unsigned int u32x4;
typedef __attribute__((ext_vector_type(2))) unsigned int u32x2;

#define NTOK 4096
#define NT32 32   // 4096 / 128 t2-tiles

#if __has_builtin(__builtin_amdgcn_exp2f)
#define EXP2F __builtin_amdgcn_exp2f
#else
#define EXP2F exp2f
#endif

__device__ __forceinline__ f32x4 MFMA(bf16x8 a, bf16x8 b, f32x4 c) {
    return __builtin_amdgcn_mfma_f32_16x16x32_bf16(a, b, c, 0, 0, 0);
}

// packed f32->bf16 (D.lo = bf16(a), D.hi = bf16(b))
__device__ __forceinline__ uint32_t pk_bf16(float a, float b) {
    uint32_t d;
    asm("v_cvt_pk_bf16_f32 %0, %1, %2" : "=v"(d) : "v"(a), "v"(b));
    return d;
}

// truncation hi/lo split of 8 floats into two bf16x8 fragments
__device__ __forceinline__ void hilo_pack8(const float* v, bf16x8* h, bf16x8* l) {
    union { uint32_t u[4]; bf16x8 b; } H, L;
#pragma unroll
    for (int m = 0; m < 4; ++m) {
        const uint32_t ua = __float_as_uint(v[2*m]);
        const uint32_t ub = __float_as_uint(v[2*m+1]);
        const float la = v[2*m]   - __uint_as_float(ua & 0xffff0000u);
        const float lb = v[2*m+1] - __uint_as_float(ub & 0xffff0000u);
        H.u[m] = (ua >> 16) | (ub & 0xffff0000u);
        L.u[m] = (__float_as_uint(la) >> 16) | (__float_as_uint(lb) & 0xffff0000u);
    }
    *h = H.b; *l = L.b;
}

// ---------------------------------------------------------------------------
// k_qkv: QKV projection via MFMA (w,x hi/lo 3-term), then repack through LDS.
// (unchanged)
// ---------------------------------------------------------------------------
__global__ __launch_bounds__(256) void k_qkv(
    const float* __restrict__ x, const float* __restrict__ wqkv, const float* __restrict__ bqkv,
    u16* __restrict__ Qp, u16* __restrict__ Kp, u16* __restrict__ Vp)
{
    __shared__ float qt_lds[64 * 194];
    const int blk = blockIdx.x;
    const int b   = blk >> 6;
    const int tb  = (blk & 63) << 6;
    const int tid = threadIdx.x;
    const int lane = tid & 63;
    const int wv  = __builtin_amdgcn_readfirstlane(tid >> 6);
    const int r   = lane & 15;
    const int g   = lane >> 4;
    const int o0  = wv * 48;

    bf16x8 wh[3][2], wl[3][2];
#pragma unroll
    for (int oi = 0; oi < 3; ++oi)
#pragma unroll
        for (int ks = 0; ks < 2; ++ks) {
            const float* wp = wqkv + (size_t)(o0 + oi*16 + r) * 64 + ks*32 + g*8;
            float wv8[8];
            *(f32x4*)(wv8)     = *(const f32x4*)(wp);
            *(f32x4*)(wv8 + 4) = *(const f32x4*)(wp + 4);
            hilo_pack8(wv8, &wh[oi][ks], &wl[oi][ks]);
        }

    f32x4 acc[3][4];
#pragma unroll
    for (int oi = 0; oi < 3; ++oi)
#pragma unroll
        for (int tt = 0; tt < 4; ++tt) acc[oi][tt] = 0.f;

#pragma unroll
    for (int tt = 0; tt < 4; ++tt) {
        bf16x8 xh[2], xl[2];
#pragma unroll
        for (int ks = 0; ks < 2; ++ks) {
            float xv[8];
#pragma unroll
            for (int j = 0; j < 8; ++j)
                xv[j] = x[(size_t)(b*64 + ks*32 + g*8 + j) * NTOK + tb + tt*16 + r];
            hilo_pack8(xv, &xh[ks], &xl[ks]);
        }
#pragma unroll
        for (int oi = 0; oi < 3; ++oi) {
            f32x4 a = acc[oi][tt];
            a = MFMA(wh[oi][0], xh[0], a);
            a = MFMA(wh[oi][1], xh[1], a);
            a = MFMA(wl[oi][0], xh[0], a);
            a = MFMA(wl[oi][1], xh[1], a);
            a = MFMA(wh[oi][0], xl[0], a);
            a = MFMA(wh[oi][1], xl[1], a);
            acc[oi][tt] = a;
        }
    }

#pragma unroll
    for (int oi = 0; oi < 3; ++oi)
#pragma unroll
        for (int tt = 0; tt < 4; ++tt)
#pragma unroll
            for (int i = 0; i < 4; ++i)
                qt_lds[(tt*16 + r) * 194 + o0 + oi*16 + g*4 + i] = acc[oi][tt][i];
    __syncthreads();

    const float SC = 0.18033688011112042f;  // (1/8) * log2(e)

    {
        const int t = tid >> 2, c0 = (tid & 3) * 16;
        float v[16], bq[16];
#pragma unroll
        for (int m = 0; m < 8; ++m)
            *(f32x2*)(v + 2*m) = *(const f32x2*)&qt_lds[t*194 + c0 + 2*m];
#pragma unroll
        for (int m = 0; m < 4; ++m)
            *(f32x4*)(bq + 4*m) = *(const f32x4*)(bqkv + c0 + 4*m);
        u32x4 P0, P1;
#pragma unroll
        for (int m = 0; m < 4; ++m) {
            P0[m] = pk_bf16((v[2*m]   + bq[2*m]  ) * SC, (v[2*m+1] + bq[2*m+1]) * SC);
            P1[m] = pk_bf16((v[8+2*m] + bq[8+2*m]) * SC, (v[9+2*m] + bq[9+2*m]) * SC);
        }
        size_t base = ((size_t)(b * NTOK + tb + t)) * 64 + c0;
        *(u32x4*)(Qp + base)     = P0;
        *(u32x4*)(Qp + base + 8) = P1;
    }

#pragma unroll
    for (int uu = 0; uu < 2; ++uu) {
        const int u  = tid * 2 + uu;
        const int t  = u >> 3;
        const int ks = (u >> 2) & 1;
        const int gk = u & 3;
        const int cb0 = 64 + ks*32 + gk*8;
        float v[8];
#pragma unroll
        for (int m = 0; m < 4; ++m)
            *(f32x2*)(v + 2*m) = *(const f32x2*)&qt_lds[t*194 + cb0 + 2*m];
        u32x4 P;
#pragma unroll
        for (int m = 0; m < 4; ++m)
            P[m] = pk_bf16(v[2*m] + bqkv[cb0 + 2*m], v[2*m+1] + bqkv[cb0 + 2*m+1]);
        const int tg = tb + t;
        size_t kbase = (size_t)b * 262144 + ((size_t)(tg >> 4) * 2 + ks) * 512 + gk*128 + (t & 15) * 8;
        *(u32x4*)(Kp + kbase) = P;
    }

    {
        const int cb = (tid >> 4) & 3;
        const int r2 = tid & 15;
        const float bv = bqkv[128 + cb*16 + r2];
        const int T = (blk & 63) >> 1;
        const int halfb = blk & 1;
#pragma unroll
        for (int m = 0; m < 4; ++m) {
            const int tq = m * 4 + (tid >> 6);
            float v[4];
#pragma unroll
            for (int jj = 0; jj < 4; ++jj)
                v[jj] = qt_lds[(tq*4 + jj)*194 + 128 + cb*16 + r2] + bv;
            const int t = tq * 4;
            const int wtr = halfb*2 + (t >> 5);
            const int sti = (t >> 4) & 1;
            const int g2  = (t >> 2) & 3;
            u32x2 W;
            W[0] = pk_bf16(v[0], v[1]);
            W[1] = pk_bf16(v[2], v[3]);
            size_t vbase = (size_t)b * 262144 +
                           (((size_t)T * 4 + wtr) * 4 + cb) * 512 + (g2*16 + r2) * 8 + sti * 4;
            *(u32x2*)(Vp + vbase) = W;
        }
    }
}

// ---------------------------------------------------------------------------
// k_attn: flash attention, fixed-shift softmax, register-only barrier-free
// main loop. grid 512 = 8 b x 64 Q-tiles (64 rows); block 256 = 4 waves,
// each wave: ALL 64 Q-rows x a 32-t2 slice of each 128-t2 tile.
// Doubling Q-rows/wave halves K/V bytes per unit work (1 GB -> 512 MB)
// against the measured ~32 B/cyc/CU vector-memory wall.
// K double-buffered (A/B reg sets); V loaded at body top (self-hiding).
// rt processed in PAIRS to cap live S-registers (R5/R8 spill lesson:
// combined arch+acc must fit 512/waves -> launch_bounds (256,2)).
// 4-way t2-slice merge (plain sums) + fused out-projection + residual.
// ---------------------------------------------------------------------------
__global__ __launch_bounds__(256, 2) void k_attn(
    const u16* __restrict__ Qp, const u16* __restrict__ Kp, const u16* __restrict__ Vp,
    const float* __restrict__ wout, const float* __restrict__ bout,
    const float* __restrict__ x, float* __restrict__ out)
{
    __shared__ float larr[4][64];
    __shared__ float otbuf[2][64 * 67];
    const int hw  = blockIdx.x;
    const int b   = hw & 7;        // batch -> XCD pinning
    const int qt  = hw >> 3;       // 0..63
    const int tid = threadIdx.x;
    const int lane = tid & 63;
    const int wt2 = tid >> 6;      // t2-slice 0..3
    const int r   = lane & 15;
    const int g   = lane >> 4;
    const int row0 = qt * 64;

    // Q fragments (B operand), rows row0 + rt*16 + r, rt = 0..3
    bf16x8 qh[4][2];
#pragma unroll
    for (int rt = 0; rt < 4; ++rt) {
        const size_t qoff = ((size_t)(b * NTOK + row0 + rt*16 + r)) * 64 + g * 8;
        qh[rt][0] = *(const bf16x8*)(Qp + qoff);
        qh[rt][1] = *(const bf16x8*)(Qp + qoff + 32);
    }

    // per-wave K/V fragment bases (tile stride 8192 elems = 16 KB)
    const u16* kbase = Kp + (size_t)b * 262144 + wt2 * 2048 + (size_t)lane * 8;
    const u16* vptr  = Vp + (size_t)b * 262144 + wt2 * 2048 + (size_t)lane * 8;

    // ones B-fragment for row-sum MFMA
    bf16x8 ONES;
#pragma unroll
    for (int j = 0; j < 8; ++j) ONES[j] = (short)0x3F80;

    f32x4 oacc[4][4];
#pragma unroll
    for (int rt = 0; rt < 4; ++rt)
#pragma unroll
        for (int cb = 0; cb < 4; ++cb) oacc[rt][cb] = 0.f;
    f32x4 lacc[4];
#pragma unroll
    for (int rt = 0; rt < 4; ++rt) lacc[rt] = 0.f;

    // preload K for tiles 0 (A) and 1 (B)
    bf16x8 kA[2][2], kB[2][2];
#pragma unroll
    for (int sti = 0; sti < 2; ++sti)
#pragma unroll
        for (int ks = 0; ks < 2; ++ks) {
            kA[sti][ks] = *(const bf16x8*)(kbase + 0*8192 + sti*1024 + ks*512);
            kB[sti][ks] = *(const bf16x8*)(kbase + 1*8192 + sti*1024 + ks*512);
        }

    auto halfrt = [&](bf16x8 (&kb)[2][2], bf16x8 (&vf)[4], int rt0) {
        // QK^T for row-tiles rt0, rt0+1 (8 MFMA)
        f32x4 s[2][2];
        __builtin_amdgcn_s_setprio(1);
#pragma unroll
        for (int rr = 0; rr < 2; ++rr)
#pragma unroll
            for (int sti = 0; sti < 2; ++sti) {
                f32x4 a = {0.f, 0.f, 0.f, 0.f};
                a = MFMA(kb[sti][0], qh[rt0 + rr][0], a);
                a = MFMA(kb[sti][1], qh[rt0 + rr][1], a);
                s[rr][sti] = a;
            }
        __builtin_amdgcn_s_setprio(0);

        // fixed-shift softmax + PV + l for the pair
#pragma unroll
        for (int rr = 0; rr < 2; ++rr) {
            const int rt = rt0 + rr;
            float p[8];
#pragma unroll
            for (int sti = 0; sti < 2; ++sti)
#pragma unroll
                for (int i = 0; i < 4; ++i)
                    p[sti*4 + i] = EXP2F(s[rr][sti][i]);
            union { uint32_t u[4]; bf16x8 b; } PA;
#pragma unroll
            for (int m = 0; m < 4; ++m) PA.u[m] = pk_bf16(p[2*m], p[2*m+1]);
            __builtin_amdgcn_s_setprio(1);
#pragma unroll
            for (int cb = 0; cb < 4; ++cb)
                oacc[rt][cb] = MFMA(PA.b, vf[cb], oacc[rt][cb]);
            lacc[rt] = MFMA(PA.b, ONES, lacc[rt]);
            __builtin_amdgcn_s_setprio(0);
        }
    };

    auto body = [&](bf16x8 (&kb)[2][2], int Tp) {
        // V fragments for this tile (consumed after QK+softmax -> self-hiding)
        bf16x8 vf[4];
#pragma unroll
        for (int cb = 0; cb < 4; ++cb)
            vf[cb] = *(const bf16x8*)(vptr + cb*512);
        vptr += 8192;

        halfrt(kb, vf, 0);
        halfrt(kb, vf, 2);

        // prefetch K for tile Tp into the register set just consumed
        const u16* kp = kbase + (size_t)Tp * 8192;
#pragma unroll
        for (int sti = 0; sti < 2; ++sti)
#pragma unroll
            for (int ks = 0; ks < 2; ++ks)
                kb[sti][ks] = *(const bf16x8*)(kp + sti*1024 + ks*512);
    };

    for (int T = 0; T < NT32; T += 2) {
        const int TpA = (T + 2 < NT32) ? T + 2 : NT32 - 1;
        const int TpB = (T + 3 < NT32) ? T + 3 : NT32 - 1;
        body(kA, TpA);
        body(kB, TpB);
    }

    // ---- epilogue: 4-way slice merge (plain sums; shift-exact softmax) ----
    if (r == 0) {
#pragma unroll
        for (int rt = 0; rt < 4; ++rt)
#pragma unroll
            for (int i = 0; i < 4; ++i)
                larr[wt2][rt*16 + g*4 + i] = lacc[rt][i];
    }

    // accumulate raw O partials (64 rows x 64 cols): wt2 0/1 write, 2/3 add
    if (wt2 < 2) {
        float* ob = otbuf[wt2];
#pragma unroll
        for (int rt = 0; rt < 4; ++rt)
#pragma unroll
            for (int cb = 0; cb < 4; ++cb)
#pragma unroll
                for (int i = 0; i < 4; ++i)
                    ob[(rt*16 + g*4 + i)*67 + cb*16 + r] = oacc[rt][cb][i];
    }
    __syncthreads();
    if (wt2 >= 2) {
        float* ob = otbuf[wt2 - 2];
#pragma unroll
        for (int rt = 0; rt < 4; ++rt)
#pragma unroll
            for (int cb = 0; cb < 4; ++cb)
#pragma unroll
                for (int i = 0; i < 4; ++i)
                    ob[(rt*16 + g*4 + i)*67 + cb*16 + r] += oacc[rt][cb][i];
    }
    __syncthreads();

    // ---- fused out-projection + bias + residual ----
    // wave wt2 handles block-local token rows wt2*16 + r, all 64 outputs
    const int orow = wt2*16 + r;
    const float inv = 1.0f / (larr[0][orow] + larr[1][orow] + larr[2][orow] + larr[3][orow]);
    bf16x8 oh_[2], ol_[2];
#pragma unroll
    for (int ks = 0; ks < 2; ++ks) {
        float ov[8];
#pragma unroll
        for (int j = 0; j < 8; ++j) {
            const int idx = orow*67 + ks*32 + g*8 + j;
            ov[j] = (otbuf[0][idx] + otbuf[1][idx]) * inv;
        }
        hilo_pack8(ov, &oh_[ks], &ol_[ks]);
    }
#pragma unroll
    for (int ot = 0; ot < 4; ++ot) {
        bf16x8 wh2[2], wl2[2];
#pragma unroll
        for (int ks = 0; ks < 2; ++ks) {
            const float* wp = wout + (size_t)(ot*16 + r) * 64 + ks*32 + g*8;
            float wv8[8];
            *(f32x4*)(wv8)     = *(const f32x4*)(wp);
            *(f32x4*)(wv8 + 4) = *(const f32x4*)(wp + 4);
            hilo_pack8(wv8, &wh2[ks], &wl2[ks]);
        }
        f32x4 a = {0.f, 0.f, 0.f, 0.f};
        a = MFMA(wh2[0], oh_[0], a);
        a = MFMA(wh2[1], oh_[1], a);
        a = MFMA(wl2[0], oh_[0], a);
        a = MFMA(wl2[1], oh_[1], a);
        a = MFMA(wh2[0], ol_[0], a);
        a = MFMA(wh2[1], ol_[1], a);
#pragma unroll
        for (int i = 0; i < 4; ++i) {
            const int oo = ot*16 + g*4 + i;
            const size_t xi = ((size_t)(b*64 + oo)) * NTOK + row0 + wt2*16 + r;
            out[xi] = a[i] + bout[oo] + x[xi];
        }
    }
}

extern "C" void kernel_launch(void* const* d_in, const int* in_sizes, int n_in,
                              void* d_out, int out_size, void* d_ws, size_t ws_size,
                              hipStream_t stream)
{
    (void)in_sizes; (void)n_in; (void)out_size; (void)ws_size;
    const float* x    = (const float*)d_in[0];
    const float* wqkv = (const float*)d_in[1];
    const float* bqkv = (const float*)d_in[2];
    const float* wout = (const float*)d_in[3];
    const float* bout = (const float*)d_in[4];
    float* out = (float*)d_out;

    char* ws = (char*)d_ws;
    const size_t MB = 1024 * 1024;
    u16* Qp = (u16*)(ws);
    u16* Kp = (u16*)(ws + 4 * MB);
    u16* Vp = (u16*)(ws + 8 * MB);

    k_qkv<<<512, 256, 0, stream>>>(x, wqkv, bqkv, Qp, Kp, Vp);
    k_attn<<<512, 256, 0, stream>>>(Qp, Kp, Vp, wout, bout, x, out);
}